// Round 8
// baseline (137.144 us; speedup 1.0000x reference)
//
#include <hip/hip_runtime.h>
#include <math.h>

constexpr int BS = 32, NV = 321, PL = 12, DM = 128;
constexpr int KT = 32;  // int(64*0.5) patches masked by time criterion
constexpr int KF = 25;  // int(64*0.4) patches masked by freq criterion
constexpr int VB = 4;       // variables per block == waves per block
constexpr int NCHUNK = 81;  // 80 full chunks + 1 tail chunk (nv=1)
constexpr int SST = 72;     // score row stride -> <=2-way LDS aliasing (free)

// map float -> uint such that uint order == float order (total, -0 < +0)
__device__ __forceinline__ unsigned ord(float f) {
  unsigned u = __float_as_uint(f);
  return ((int)u < 0) ? ~u : (u | 0x80000000u);
}

// ---------------------------------------------------------------------------
// prep: M = W_in @ W_out (12x12), c = b_in @ W_out (12),
//       S_t = tt*colsum(W_out), S_f = ft*colsum(W_out), copy of b_out.
// prep floats: [0,144) M [i][l], [144,156) c, [156,168) S_t, [168,180) S_f,
//              [180,192) b_out
// ---------------------------------------------------------------------------
__global__ void prep_kernel(const float* __restrict__ W_in,
                            const float* __restrict__ b_in,
                            const float* __restrict__ W_out,
                            const float* __restrict__ b_out,
                            const float* __restrict__ tt,
                            const float* __restrict__ ft,
                            float* __restrict__ prep) {
  int t = threadIdx.x;
  if (t < 144) {
    int i = t / 12, l = t % 12;
    const float4* Wi = (const float4*)(W_in + i * DM);
    float s = 0.f;
#pragma unroll 8
    for (int d4 = 0; d4 < 32; ++d4) {
      float4 a = Wi[d4];
      const float* wo = W_out + d4 * 48 + l;
      s += a.x * wo[0] + a.y * wo[12] + a.z * wo[24] + a.w * wo[36];
    }
    prep[t] = s;
  } else if (t < 168) {
    int l = (t - 144) % 12;
    float cs = 0.f, cb = 0.f;
#pragma unroll 8
    for (int d = 0; d < DM; ++d) {
      float w = W_out[d * 12 + l];
      cs += w;
      cb += b_in[d] * w;
    }
    if (t < 156) {
      prep[144 + l] = cb;
      prep[156 + l] = tt[0] * cs;
    } else {
      prep[168 + l] = ft[0] * cs;
    }
  } else if (t < 180) {
    prep[180 + (t - 168)] = b_out[t - 168];
  }
}

// ---------------------------------------------------------------------------
// fused: one block per (b, 4-var chunk); thread <-> one patch
// (p = t>>2, vv = t&3; lanes sweep vv -> 192B contiguous global runs).
//   scores -> LDS -> barrier -> [ballot-radix rank (wave wv ranks group wv,
//   serial VALU->SALU chain) INTERLEAVED with decode E = x.M + c (144
//   v_fmac with SGPR operands from uniform prep[])] -> barrier -> epilogue.
// The decode FMA stream hides the radix latency; zero LDS traffic for M.
// ---------------------------------------------------------------------------
__global__ __launch_bounds__(256, 8) void fused_kernel(
    const float* __restrict__ x, const float* __restrict__ prep,
    float* __restrict__ out) {
  __shared__ float scv[VB * SST];
  __shared__ float sfs[VB * SST];
  __shared__ unsigned long long smT[VB], smF[VB];

  const int t = threadIdx.x;
  const int chunk = blockIdx.x;  // 0..80
  const int b = blockIdx.y;      // 0..31
  const int v0 = chunk * VB;
  const bool full = (chunk < 80);
  const int p = t >> 2;  // 0..63
  const int vv = t & 3;  // 0..3
  const bool valid = full || (vv == 0);

  // ---- load this thread's patch (3 independent dwordx4) ----
  float xr[12];
  if (valid) {
    const float4* src =
        (const float4*)(x + (((size_t)(b * 64 + p) * NV) + v0 + vv) * PL);
    float4 a = src[0], bb = src[1], c = src[2];
    xr[0] = a.x;  xr[1] = a.y;  xr[2] = a.z;  xr[3] = a.w;
    xr[4] = bb.x; xr[5] = bb.y; xr[6] = bb.z; xr[7] = bb.w;
    xr[8] = c.x;  xr[9] = c.y;  xr[10] = c.z; xr[11] = c.w;
  }

  // ---- scores from registers; 2 floats/patch to LDS ----
  const float H = 0.86602540378443864676f;  // sqrt(3)/2
  if (valid) {
    const float* xv = xr;
    // coefficient of variation: std(ddof=1)/(mean+1e-6)
    float s = 0.f;
#pragma unroll
    for (int i = 0; i < 12; ++i) s += xv[i];
    const float m = s * (1.0f / 12.0f);
    float ss = 0.f;
#pragma unroll
    for (int i = 0; i < 12; ++i) {
      float d = xv[i] - m;
      ss += d * d;
    }
    const float cv = sqrtf(ss * (1.0f / 11.0f)) / (m + 1e-6f);

    // mean |rfft12| over 7 bins, even/odd folded exact 30-degree DFT
    const float e1 = xv[1] + xv[11], e2 = xv[2] + xv[10], e3 = xv[3] + xv[9],
                e4 = xv[4] + xv[8], e5 = xv[5] + xv[7];
    const float o1 = xv[1] - xv[11], o2 = xv[2] - xv[10], o3 = xv[3] - xv[9],
                o4 = xv[4] - xv[8], o5 = xv[5] - xv[7];
    float mag = fabsf(xv[0] + xv[6] + e1 + e2 + e3 + e4 + e5);  // k=0
    float re = xv[0] - xv[6] + H * (e1 - e5) + 0.5f * (e2 - e4);
    float im = 0.5f * (o1 + o5) + H * (o2 + o4) + o3;
    mag += sqrtf(re * re + im * im);  // k=1
    re = xv[0] + xv[6] + 0.5f * (e1 + e5) - 0.5f * (e2 + e4) - e3;
    im = H * (o1 + o2 - o4 - o5);
    mag += sqrtf(re * re + im * im);  // k=2
    re = xv[0] - xv[6] - e2 + e4;
    im = o1 - o3 + o5;
    mag += sqrtf(re * re + im * im);  // k=3
    re = xv[0] + xv[6] - 0.5f * (e1 + e2 + e4 + e5) + e3;
    im = H * (o1 - o2 + o4 - o5);
    mag += sqrtf(re * re + im * im);  // k=4
    re = xv[0] - xv[6] + H * (e5 - e1) + 0.5f * (e2 - e4);
    im = 0.5f * (o1 + o5) - H * (o2 + o4) + o3;
    mag += sqrtf(re * re + im * im);  // k=5
    re = xv[0] + xv[6] - e1 + e2 - e3 + e4 - e5;
    mag += fabsf(re);  // k=6
    const float fs = mag * (1.0f / 7.0f);

    scv[vv * SST + p] = cv;  // banks (vv*8+p)%32: exact 2-way -> free
    sfs[vv * SST + p] = fs;
  }
  __syncthreads();

  // ---- dual ballot radix (wave wv ranks group wv) + decode, interleaved ----
  const int wv = t >> 6, lane = t & 63;
  if (full || wv == 0) {  // wave-uniform
    const unsigned ut = ord(scv[wv * SST + lane]);   // rank KT LARGEST cv
    const unsigned uf = ~ord(sfs[wv * SST + lane]);  // rank KF SMALLEST fs
    unsigned tht = 0, thf = 0;
#pragma unroll
    for (int bit = 31; bit >= 0; --bit) {
      const unsigned ct = tht | (1u << bit);
      const unsigned cf = thf | (1u << bit);
      const unsigned long long bt = __ballot(ut >= ct);
      const unsigned long long bf = __ballot(uf >= cf);
      if (__popcll(bt) >= KT) tht = ct;  // tht -> K-th largest key
      if (__popcll(bf) >= KF) thf = cf;
    }
    const unsigned long long pre = (1ull << lane) - 1ull;
    const int gt_t = __popcll(__ballot(ut > tht));
    const int rt = __popcll(__ballot(ut == tht) & pre);
    const bool masked_t = (ut > tht) || ((ut == tht) && (rt < KT - gt_t));
    const int gt_f = __popcll(__ballot(uf > thf));
    const int rf = __popcll(__ballot(uf == thf) & pre);
    const bool masked_f = (uf > thf) || ((uf == thf) && (rf < KF - gt_f));
    const unsigned long long bkt = __ballot(!masked_t);
    const unsigned long long bkf = __ballot(!masked_f);
    if (lane == 0) {
      smT[wv] = bkt;
      smF[wv] = bkf;
    }
  }

  // decode E = x.M + c: uniform prep[] -> s_load + v_fmac(sgpr); independent
  // of the radix chain above -> compiler co-schedules VALU fma with SALU radix
  float E[12];
#pragma unroll
  for (int l = 0; l < 12; ++l) E[l] = prep[144 + l];
#pragma unroll
  for (int i = 0; i < 12; ++i) {
    const float a = xr[i];
#pragma unroll
    for (int l = 0; l < 12; ++l) E[l] += a * prep[i * 12 + l];
  }
  __syncthreads();

  // ---- epilogue: masks from LDS, blend, coalesced float4 stores ----
  if (valid) {
    const bool kt = (smT[vv] >> p) & 1ull;
    const bool kf = (smF[vv] >> p) & 1ull;
    float o[12];
#pragma unroll
    for (int l = 0; l < 12; ++l) {
      const float at = kt ? E[l] : prep[156 + l];
      const float af = kf ? E[l] : prep[168 + l];
      o[l] = 0.5f * (at + af) + prep[180 + l];
    }
    float* op = out + (((size_t)(b * 64 + p) * NV) + v0 + vv) * PL;
    ((float4*)op)[0] = make_float4(o[0], o[1], o[2], o[3]);
    ((float4*)op)[1] = make_float4(o[4], o[5], o[6], o[7]);
    ((float4*)op)[2] = make_float4(o[8], o[9], o[10], o[11]);
  }
}

extern "C" void kernel_launch(void* const* d_in, const int* in_sizes, int n_in,
                              void* d_out, int out_size, void* d_ws,
                              size_t ws_size, hipStream_t stream) {
  const float* x = (const float*)d_in[0];
  const float* W_in = (const float*)d_in[1];
  const float* b_in = (const float*)d_in[2];
  const float* W_out = (const float*)d_in[3];
  const float* b_out = (const float*)d_in[4];
  const float* tt = (const float*)d_in[5];
  const float* ft = (const float*)d_in[6];
  float* out = (float*)d_out;
  float* prep = (float*)d_ws;  // 192 floats

  hipLaunchKernelGGL(prep_kernel, dim3(1), dim3(192), 0, stream, W_in, b_in,
                     W_out, b_out, tt, ft, prep);
  hipLaunchKernelGGL(fused_kernel, dim3(NCHUNK, BS), dim3(256), 0, stream, x,
                     prep, out);
}

// Round 9
// 118.949 us; speedup vs baseline: 1.1530x; 1.1530x over previous
//
#include <hip/hip_runtime.h>
#include <math.h>

constexpr int BS = 32, NP = 64, NV = 321, PL = 12, DM = 128;
constexpr int KT = 32;  // int(64*0.5) patches masked by time criterion
constexpr int KF = 25;  // int(64*0.4) patches masked by freq criterion
constexpr int ROWF = NV * PL;  // 3852 floats per (b,p) row

// ws layout (bytes)
constexpr size_t SCORES_OFF = 0;                     // float2[BS*NP*NV] 5.25 MB
constexpr size_t MASKS_OFF = (size_t)BS * NP * NV * 8;        // ulonglong2[BS*NV]
constexpr size_t PREP_OFF = MASKS_OFF + (size_t)BS * NV * 16; // float[192]

// map float -> uint such that uint order == float order (total, -0 < +0)
__device__ __forceinline__ unsigned ord(float f) {
  unsigned u = __float_as_uint(f);
  return ((int)u < 0) ? ~u : (u | 0x80000000u);
}

__device__ __forceinline__ void compute_scores(const float* xv, float& cv,
                                               float& fs) {
  const float H = 0.86602540378443864676f;  // sqrt(3)/2
  // coefficient of variation: std(ddof=1)/(mean+1e-6)
  float s = 0.f;
#pragma unroll
  for (int i = 0; i < 12; ++i) s += xv[i];
  const float m = s * (1.0f / 12.0f);
  float ss = 0.f;
#pragma unroll
  for (int i = 0; i < 12; ++i) {
    float d = xv[i] - m;
    ss += d * d;
  }
  cv = sqrtf(ss * (1.0f / 11.0f)) / (m + 1e-6f);
  // mean |rfft12| over 7 bins, even/odd folded exact 30-degree DFT
  const float e1 = xv[1] + xv[11], e2 = xv[2] + xv[10], e3 = xv[3] + xv[9],
              e4 = xv[4] + xv[8], e5 = xv[5] + xv[7];
  const float o1 = xv[1] - xv[11], o2 = xv[2] - xv[10], o3 = xv[3] - xv[9],
              o4 = xv[4] - xv[8], o5 = xv[5] - xv[7];
  float mag = fabsf(xv[0] + xv[6] + e1 + e2 + e3 + e4 + e5);  // k=0
  float re = xv[0] - xv[6] + H * (e1 - e5) + 0.5f * (e2 - e4);
  float im = 0.5f * (o1 + o5) + H * (o2 + o4) + o3;
  mag += sqrtf(re * re + im * im);  // k=1
  re = xv[0] + xv[6] + 0.5f * (e1 + e5) - 0.5f * (e2 + e4) - e3;
  im = H * (o1 + o2 - o4 - o5);
  mag += sqrtf(re * re + im * im);  // k=2
  re = xv[0] - xv[6] - e2 + e4;
  im = o1 - o3 + o5;
  mag += sqrtf(re * re + im * im);  // k=3
  re = xv[0] + xv[6] - 0.5f * (e1 + e2 + e4 + e5) + e3;
  im = H * (o1 - o2 + o4 - o5);
  mag += sqrtf(re * re + im * im);  // k=4
  re = xv[0] - xv[6] + H * (e5 - e1) + 0.5f * (e2 - e4);
  im = 0.5f * (o1 + o5) - H * (o2 + o4) + o3;
  mag += sqrtf(re * re + im * im);  // k=5
  re = xv[0] + xv[6] - e1 + e2 - e3 + e4 - e5;
  mag += fabsf(re);  // k=6
  fs = mag * (1.0f / 7.0f);
}

// ---------------------------------------------------------------------------
// A: block = (b,p) row of x, 15,408 B CONTIGUOUS. Thread t<321 loads its
// var's 48 B at byte offset 48t -> a wave's addresses are fully sequential
// (3 KB span, every line consecutive) -> DRAM streaming, unlike the
// 15 KB-stride gather of rounds 4-8. Scores written contiguous (float2).
// Block 2048 computes the collapsed decode constants instead.
// ---------------------------------------------------------------------------
__global__ __launch_bounds__(384) void score_prep_kernel(
    const float* __restrict__ x, const float* __restrict__ W_in,
    const float* __restrict__ b_in, const float* __restrict__ W_out,
    const float* __restrict__ b_out, const float* __restrict__ tt,
    const float* __restrict__ ft, float2* __restrict__ scores,
    float* __restrict__ prep) {
  const int t = threadIdx.x;
  if (blockIdx.x == BS * NP) {  // ---- prep block ----
    if (t < 144) {
      const int i = t / 12, l = t - (t / 12) * 12;
      const float4* Wi = (const float4*)(W_in + i * DM);
      float s = 0.f;
#pragma unroll 8
      for (int d4 = 0; d4 < 32; ++d4) {
        float4 a = Wi[d4];
        const float* wo = W_out + d4 * 48 + l;
        s += a.x * wo[0] + a.y * wo[12] + a.z * wo[24] + a.w * wo[36];
      }
      prep[t] = s;
    } else if (t < 168) {
      const int l = (t - 144) % 12;
      float cs = 0.f, cb = 0.f;
#pragma unroll 8
      for (int d = 0; d < DM; ++d) {
        float w = W_out[d * 12 + l];
        cs += w;
        cb += b_in[d] * w;
      }
      if (t < 156) {
        prep[144 + l] = cb;
        prep[156 + l] = tt[0] * cs;
      } else {
        prep[168 + l] = ft[0] * cs;
      }
    } else if (t < 180) {
      prep[180 + (t - 168)] = b_out[t - 168];
    }
    return;
  }
  if (t >= NV) return;
  const int bp = blockIdx.x;
  const float4* src = (const float4*)(x + (size_t)bp * ROWF + t * PL);
  const float4 a = src[0], b4 = src[1], c4 = src[2];
  const float xv[12] = {a.x,  a.y,  a.z,  a.w,  b4.x, b4.y,
                        b4.z, b4.w, c4.x, c4.y, c4.z, c4.w};
  float cv, fs;
  compute_scores(xv, cv, fs);
  scores[(size_t)bp * NV + t] = make_float2(cv, fs);
}

// ---------------------------------------------------------------------------
// B: dual ballot-radix top-k. Wave wv ranks vars chunk*8+wv*2+{0,1}; lane=p.
// Score loads are 8 B/lane stride-2568 gathers of L3-resident data (5.25 MB).
// ---------------------------------------------------------------------------
__global__ __launch_bounds__(256) void rank_kernel(
    const float2* __restrict__ scores, ulonglong2* __restrict__ masks) {
  const int chunk = blockIdx.x;  // 0..40
  const int b = blockIdx.y;      // 0..31
  const int wv = threadIdx.x >> 6, lane = threadIdx.x & 63;
#pragma unroll
  for (int h = 0; h < 2; ++h) {
    const int v = chunk * 8 + wv * 2 + h;
    if (v < NV) {  // wave-uniform
      const float2 s2 = scores[(size_t)(b * 64 + lane) * NV + v];
      const unsigned ut = ord(s2.x);   // rank KT LARGEST cv
      const unsigned uf = ~ord(s2.y);  // rank KF SMALLEST fs
      unsigned tht = 0, thf = 0;
#pragma unroll
      for (int bit = 31; bit >= 0; --bit) {
        const unsigned ct = tht | (1u << bit);
        const unsigned cf = thf | (1u << bit);
        const unsigned long long bt = __ballot(ut >= ct);
        const unsigned long long bf = __ballot(uf >= cf);
        if (__popcll(bt) >= KT) tht = ct;  // -> K-th largest key
        if (__popcll(bf) >= KF) thf = cf;
      }
      const unsigned long long pre = (1ull << lane) - 1ull;
      const int gt_t = __popcll(__ballot(ut > tht));
      const int rt = __popcll(__ballot(ut == tht) & pre);
      const bool masked_t = (ut > tht) || ((ut == tht) && (rt < KT - gt_t));
      const int gt_f = __popcll(__ballot(uf > thf));
      const int rf = __popcll(__ballot(uf == thf) & pre);
      const bool masked_f = (uf > thf) || ((uf == thf) && (rf < KF - gt_f));
      const unsigned long long bkt = __ballot(!masked_t);
      const unsigned long long bkf = __ballot(!masked_f);
      if (lane == 0) masks[b * NV + v] = make_ulonglong2(bkt, bkf);
    }
  }
}

// ---------------------------------------------------------------------------
// C: block = (b,p) row. Streams x (L3-warm from A), masks as coalesced
// 16 B/thread, decode via LDS-staged M b128 broadcasts (r7's VALU-light
// path), CONTIGUOUS 48 B/thread stores (wave spans 3 KB sequential).
// ---------------------------------------------------------------------------
__global__ __launch_bounds__(384) void decode_kernel(
    const float* __restrict__ x, const ulonglong2* __restrict__ masks,
    const float* __restrict__ prep, float* __restrict__ out) {
  __shared__ __align__(16) float spp[192];  // M(144) c(12) St(12) Sf(12) b(12)
  const int t = threadIdx.x;
  if (t < 192) spp[t] = prep[t];
  __syncthreads();
  if (t >= NV) return;
  const int bp = blockIdx.x;  // b*64 + p
  const int b = bp >> 6, p = bp & 63;

  const float4* src = (const float4*)(x + (size_t)bp * ROWF + t * PL);
  const float4 a = src[0], b4 = src[1], c4 = src[2];
  const float xv[12] = {a.x,  a.y,  a.z,  a.w,  b4.x, b4.y,
                        b4.z, b4.w, c4.x, c4.y, c4.z, c4.w};
  const ulonglong2 mk = masks[b * NV + t];
  const bool kt = (mk.x >> p) & 1ull;
  const bool kf = (mk.y >> p) & 1ull;

  float E[12];
#pragma unroll
  for (int l = 0; l < 12; ++l) E[l] = spp[144 + l];
  const float4* M4 = (const float4*)spp;
#pragma unroll
  for (int i = 0; i < 12; ++i) {  // uniform-address b128 broadcasts
    const float4 m0 = M4[i * 3], m1 = M4[i * 3 + 1], m2 = M4[i * 3 + 2];
    const float av = xv[i];
    E[0] += av * m0.x;  E[1] += av * m0.y;  E[2] += av * m0.z;  E[3] += av * m0.w;
    E[4] += av * m1.x;  E[5] += av * m1.y;  E[6] += av * m1.z;  E[7] += av * m1.w;
    E[8] += av * m2.x;  E[9] += av * m2.y;  E[10] += av * m2.z; E[11] += av * m2.w;
  }
  float o[12];
#pragma unroll
  for (int l = 0; l < 12; ++l) {
    const float at = kt ? E[l] : spp[156 + l];
    const float af = kf ? E[l] : spp[168 + l];
    o[l] = 0.5f * (at + af) + spp[180 + l];
  }
  float4* dst = (float4*)(out + (size_t)bp * ROWF + t * PL);
  dst[0] = make_float4(o[0], o[1], o[2], o[3]);
  dst[1] = make_float4(o[4], o[5], o[6], o[7]);
  dst[2] = make_float4(o[8], o[9], o[10], o[11]);
}

extern "C" void kernel_launch(void* const* d_in, const int* in_sizes, int n_in,
                              void* d_out, int out_size, void* d_ws,
                              size_t ws_size, hipStream_t stream) {
  const float* x = (const float*)d_in[0];
  const float* W_in = (const float*)d_in[1];
  const float* b_in = (const float*)d_in[2];
  const float* W_out = (const float*)d_in[3];
  const float* b_out = (const float*)d_in[4];
  const float* tt = (const float*)d_in[5];
  const float* ft = (const float*)d_in[6];
  float* out = (float*)d_out;

  float2* scores = (float2*)((char*)d_ws + SCORES_OFF);
  ulonglong2* masks = (ulonglong2*)((char*)d_ws + MASKS_OFF);
  float* prep = (float*)((char*)d_ws + PREP_OFF);

  hipLaunchKernelGGL(score_prep_kernel, dim3(BS * NP + 1), dim3(384), 0,
                     stream, x, W_in, b_in, W_out, b_out, tt, ft, scores, prep);
  hipLaunchKernelGGL(rank_kernel, dim3(41, BS), dim3(256), 0, stream, scores,
                     masks);
  hipLaunchKernelGGL(decode_kernel, dim3(BS * NP), dim3(384), 0, stream, x,
                     masks, prep, out);
}